// Round 1
// baseline (2088.215 us; speedup 1.0000x reference)
//
#include <hip/hip_runtime.h>
#include <math.h>

// VQ-VAE EMA vector quantizer, MI355X fp32 baseline.
// N=32768 rows (b,h,w), D=256, K=8192.

#define KC 8192
#define DD 256
#define NV 32768

// ---------- enorm[k] = sum_d embed[d,k]^2 ----------
__global__ void k_enorm(const float* __restrict__ embed, float* __restrict__ enorm) {
    int k = blockIdx.x * 256 + threadIdx.x;
    float s = 0.f;
    for (int d = 0; d < DD; ++d) { float v = embed[(size_t)d * KC + k]; s += v * v; }
    enorm[k] = s;
}

// ---------- embedT[k][d] = embed[d][k] ----------
__global__ void k_transpose_embed(const float* __restrict__ embed, float* __restrict__ embedT) {
    int kt = blockIdx.x & 255, dt = blockIdx.x >> 8;
    int k0 = kt * 32, d0 = dt * 32;
    __shared__ float tile[32][33];
    int t = threadIdx.x;
    int kk = t & 31, ii = t >> 5;
    for (int p = 0; p < 4; ++p) {
        int d = ii + p * 8;
        tile[d][kk] = embed[(size_t)(d0 + d) * KC + k0 + kk];
    }
    __syncthreads();
    int ddv = t & 31, kk2 = t >> 5;
    for (int p = 0; p < 4; ++p) {
        int k = kk2 + p * 8;
        embedT[(size_t)(k0 + k) * DD + d0 + ddv] = tile[ddv][k];
    }
}

// ---------- fused stage + argmin + xT + loss partials ----------
// block: 256 thr, 64 rows (2 (b,h) pairs x 32 w). grid 512.
__global__ __launch_bounds__(256, 2) void k_argmin(
    const float* __restrict__ x, const float* __restrict__ embed,
    const float* __restrict__ enorm, int* __restrict__ idx,
    float* __restrict__ xT, float* __restrict__ lossAcc) {
    __shared__ float xs[256][68];   // [d][row], pad 68 keeps 16B align + tames conflicts
    __shared__ float red[4];
    const int t = threadIdx.x;
    const int n0 = blockIdx.x * 64;
    const int b = n0 >> 10;
    const int h0 = (n0 >> 5) & 31;

    // ---- stage x tile (coalesced float4 along w), accumulate sum(x^2) ----
    {
        const int p = t >> 7, tt = t & 127;
        const int wq = (tt & 7) * 4, d0 = tt >> 3;
        const float* src = x + (size_t)b * 262144 + (size_t)(h0 + p) * 32 + wq;
        float s2 = 0.f;
        #pragma unroll
        for (int i = 0; i < 16; ++i) {
            int d = d0 + i * 16;
            float4 v = *(const float4*)(src + (size_t)d * 1024);
            *(float4*)&xs[d][p * 32 + wq] = v;
            s2 += v.x * v.x + v.y * v.y + v.z * v.z + v.w * v.w;
        }
        for (int off = 32; off > 0; off >>= 1) s2 += __shfl_xor(s2, off);
        if ((t & 63) == 0) red[t >> 6] = s2;
    }
    __syncthreads();
    if (t == 0) atomicAdd(&lossAcc[1], red[0] + red[1] + red[2] + red[3]);

    // ---- write xT [n][d] for the segment-sum kernel (coalesced along d) ----
    {
        const int rr = t & 3, c = t >> 2;
        #pragma unroll
        for (int i = 0; i < 16; ++i) {
            int r = rr + i * 4;
            float4 f;
            f.x = xs[c * 4 + 0][r]; f.y = xs[c * 4 + 1][r];
            f.z = xs[c * 4 + 2][r]; f.w = xs[c * 4 + 3][r];
            *(float4*)(xT + (size_t)(n0 + r) * DD + c * 4) = f;
        }
    }

    // ---- distance GEMM + running argmin ----
    // wave ty owns rows ty*16..+15 (x broadcast across lanes); lane tx owns k = kbase+tx+64j.
    const int tx = t & 63, ty = t >> 6;
    float minv[16];
    int mini[16];
    #pragma unroll
    for (int m = 0; m < 16; ++m) { minv[m] = 3.4e38f; mini[m] = 0; }

    for (int kt = 0; kt < 32; ++kt) {
        const int k0 = kt * 256 + tx;
        float acc[16][4];
        #pragma unroll
        for (int m = 0; m < 16; ++m)
            #pragma unroll
            for (int j = 0; j < 4; ++j) acc[m][j] = 0.f;

        const float* ep = embed + k0;
        for (int d = 0; d < 256; ++d) {
            float e0 = ep[0], e1 = ep[64], e2 = ep[128], e3 = ep[192];
            ep += KC;
            const float4* xr = (const float4*)&xs[d][ty * 16];
            float4 a0 = xr[0], a1 = xr[1], a2 = xr[2], a3 = xr[3];
            float xm[16] = {a0.x, a0.y, a0.z, a0.w, a1.x, a1.y, a1.z, a1.w,
                            a2.x, a2.y, a2.z, a2.w, a3.x, a3.y, a3.z, a3.w};
            #pragma unroll
            for (int m = 0; m < 16; ++m) {
                acc[m][0] += xm[m] * e0;
                acc[m][1] += xm[m] * e1;
                acc[m][2] += xm[m] * e2;
                acc[m][3] += xm[m] * e3;
            }
        }
        #pragma unroll
        for (int j = 0; j < 4; ++j) {
            int kk = k0 + j * 64;
            float en = enorm[kk];
            #pragma unroll
            for (int m = 0; m < 16; ++m) {
                float dv = en - 2.f * acc[m][j];
                if (dv < minv[m]) { minv[m] = dv; mini[m] = kk; }
            }
        }
    }

    // ---- wave argmin reduce, write idx + loss partial ----
    float lsum = 0.f;
    #pragma unroll
    for (int m = 0; m < 16; ++m) {
        float v = minv[m]; int ii = mini[m];
        for (int off = 32; off > 0; off >>= 1) {
            float v2 = __shfl_xor(v, off);
            int i2 = __shfl_xor(ii, off);
            if (v2 < v || (v2 == v && i2 < ii)) { v = v2; ii = i2; }
        }
        if (tx == 0) { idx[n0 + ty * 16 + m] = ii; lsum += v; }
    }
    if (tx == 0) atomicAdd(&lossAcc[0], lsum);
}

// ---------- histogram ----------
__global__ void k_hist(const int* __restrict__ idx, int* __restrict__ cnt) {
    int n = blockIdx.x * 256 + threadIdx.x;
    atomicAdd(&cnt[idx[n]], 1);
}

// ---------- single-block: new_cluster_size, loss, perplexity, smoothed, offsets ----------
__global__ void k_stats(const int* __restrict__ cnt, const float* __restrict__ cluster_size,
                        const float* __restrict__ lossAcc,
                        float* __restrict__ out_ncs, float* __restrict__ out_loss,
                        float* __restrict__ out_perp,
                        float* __restrict__ smoothed, int* __restrict__ offsets) {
    __shared__ float rn[256], rp[256];
    __shared__ int rc[256];
    __shared__ int base_s[256];
    int t = threadIdx.x;
    float s_n = 0.f, s_pl = 0.f;
    int s_c = 0;
    float ncs_loc[32];
    #pragma unroll
    for (int i = 0; i < 32; ++i) {
        int k = t * 32 + i;
        int ci = cnt[k];
        float c = (float)ci;
        float ncs = cluster_size[k] * 0.99f + 0.01f * c;
        out_ncs[k] = ncs;
        ncs_loc[i] = ncs;
        s_n += ncs;
        float p = c * (1.0f / 32768.0f);
        s_pl += p * logf(p + 1e-10f);
        s_c += ci;
    }
    rn[t] = s_n; rp[t] = s_pl; rc[t] = s_c;
    for (int off = 128; off > 0; off >>= 1) {
        __syncthreads();
        if (t < off) { rn[t] += rn[t + off]; rp[t] += rp[t + off]; }
    }
    __syncthreads();
    float ntot = rn[0];
    if (t == 0) {
        out_loss[0] = 0.25f * (lossAcc[0] + lossAcc[1]) * (1.0f / 8388608.0f);
        out_perp[0] = expf(-rp[0]);
    }
    #pragma unroll
    for (int i = 0; i < 32; ++i) {
        int k = t * 32 + i;
        float ncs = ncs_loc[i];
        smoothed[k] = ntot * (ncs + 1e-5f) / (ntot + ncs * 1e-5f);
    }
    __syncthreads();
    if (t == 0) {
        int run = 0;
        for (int q = 0; q < 256; ++q) { base_s[q] = run; run += rc[q]; }
    }
    __syncthreads();
    int run = base_s[t];
    #pragma unroll
    for (int i = 0; i < 32; ++i) {
        int k = t * 32 + i;
        offsets[k] = run;
        run += cnt[k];
    }
}

// ---------- counting-sort scatter ----------
__global__ void k_scatter(const int* __restrict__ idx, const int* __restrict__ offsets,
                          int* __restrict__ cursor, int* __restrict__ order) {
    int n = blockIdx.x * 256 + threadIdx.x;
    int k = idx[n];
    int pos = offsets[k] + atomicAdd(&cursor[k], 1);
    order[pos] = n;
}

// ---------- dwT[k][d] = segment_sum ----------
__global__ void k_dw(const int* __restrict__ cnt, const int* __restrict__ offsets,
                     const int* __restrict__ order, const float* __restrict__ xT,
                     float* __restrict__ dwT) {
    int k = blockIdx.x;
    int t = threadIdx.x;
    int c = cnt[k], base = offsets[k];
    float s = 0.f;
    for (int i = 0; i < c; ++i) {
        int n = order[base + i];
        s += xT[(size_t)n * DD + t];
    }
    dwT[(size_t)k * DD + t] = s;
}

// ---------- new_ema_embed / new_embed (LDS-transposed, coalesced along k) ----------
__global__ void k_update_embed(const float* __restrict__ dwT, const float* __restrict__ ema_embed,
                               const float* __restrict__ smoothed,
                               float* __restrict__ out_embed, float* __restrict__ out_ema) {
    __shared__ float tile[32][260];
    int bx = blockIdx.x, t = threadIdx.x;
    int d0 = (bx & 7) * 32, k0 = (bx >> 3) * 256;
    {
        int kk = t >> 3, dq = (t & 7) * 4;
        for (int i = 0; i < 8; ++i) {
            int kl = kk + i * 32;
            float4 v = *(const float4*)(dwT + (size_t)(k0 + kl) * DD + d0 + dq);
            tile[dq + 0][kl] = v.x; tile[dq + 1][kl] = v.y;
            tile[dq + 2][kl] = v.z; tile[dq + 3][kl] = v.w;
        }
    }
    __syncthreads();
    float sm = smoothed[k0 + t];
    for (int ddv = 0; ddv < 32; ++ddv) {
        size_t o = (size_t)(d0 + ddv) * KC + k0 + t;
        float dw = tile[ddv][t];
        float ne = ema_embed[o] * 0.99f + 0.01f * dw;
        out_ema[o] = ne;
        out_embed[o] = ne / sm;
    }
}

// ---------- quantize gather + NCHW writeback ----------
__global__ __launch_bounds__(256, 2) void k_quantize_out(
    const int* __restrict__ idx, const float* __restrict__ embedT, float* __restrict__ out) {
    __shared__ float q[256][68];
    __shared__ int li[64];
    int t = threadIdx.x;
    int n0 = blockIdx.x * 64;
    int b = n0 >> 10, h0 = (n0 >> 5) & 31;
    if (t < 64) li[t] = idx[n0 + t];
    __syncthreads();
    {
        int r = t >> 2, dq4 = (t & 3) * 4;
        const float* src = embedT + (size_t)li[r] * DD;
        for (int i = 0; i < 16; ++i) {
            int d = dq4 + i * 16;
            float4 v = *(const float4*)(src + d);
            q[d + 0][r] = v.x; q[d + 1][r] = v.y;
            q[d + 2][r] = v.z; q[d + 3][r] = v.w;
        }
    }
    __syncthreads();
    {
        int p = t >> 7, tt = t & 127;
        int wq = (tt & 7) * 4, d0 = tt >> 3;
        float* dst = out + (size_t)b * 262144 + (size_t)(h0 + p) * 32 + wq;
        for (int i = 0; i < 16; ++i) {
            int d = d0 + i * 16;
            float4 v = *(const float4*)&q[d][p * 32 + wq];
            *(float4*)(dst + (size_t)d * 1024) = v;
        }
    }
}

extern "C" void kernel_launch(void* const* d_in, const int* in_sizes, int n_in,
                              void* d_out, int out_size, void* d_ws, size_t ws_size,
                              hipStream_t stream) {
    (void)in_sizes; (void)n_in; (void)out_size; (void)ws_size;
    const float* x            = (const float*)d_in[0];
    const float* embed        = (const float*)d_in[1];
    const float* cluster_size = (const float*)d_in[2];
    const float* ema_embed    = (const float*)d_in[3];
    float* out = (float*)d_out;
    char* ws = (char*)d_ws;

    float* xT       = (float*)(ws + 0);          // 33,554,432 B
    float* embedT   = (float*)(ws + 33554432);   //  8,388,608 B
    float* dwT      = (float*)(ws + 41943040);   //  8,388,608 B
    float* enorm    = (float*)(ws + 50331648);   //     32,768 B
    float* smoothed = (float*)(ws + 50364416);   //     32,768 B
    int*   idx      = (int*)  (ws + 50397184);   //    131,072 B
    int*   order    = (int*)  (ws + 50528256);   //    131,072 B
    int*   cnt      = (int*)  (ws + 50659328);   //     32,768 B
    int*   cursor   = (int*)  (ws + 50692096);   //     32,768 B
    int*   offsets  = (int*)  (ws + 50724864);   //     32,768 B
    float* lossAcc  = (float*)(ws + 50757632);   //          8 B

    float* out_q    = out;
    float* out_loss = out + 8388608;
    float* out_perp = out + 8388609;
    float* out_ncs  = out + 8388610;
    float* out_emb  = out + 8396802;
    float* out_ema  = out + 10493954;

    hipMemsetAsync(cnt, 0, 65536, stream);   // cnt + cursor (adjacent)
    hipMemsetAsync(lossAcc, 0, 8, stream);

    k_enorm<<<32, 256, 0, stream>>>(embed, enorm);
    k_transpose_embed<<<2048, 256, 0, stream>>>(embed, embedT);
    k_argmin<<<512, 256, 0, stream>>>(x, embed, enorm, idx, xT, lossAcc);
    k_hist<<<128, 256, 0, stream>>>(idx, cnt);
    k_stats<<<1, 256, 0, stream>>>(cnt, cluster_size, lossAcc, out_ncs, out_loss, out_perp,
                                   smoothed, offsets);
    k_scatter<<<128, 256, 0, stream>>>(idx, offsets, cursor, order);
    k_dw<<<8192, 256, 0, stream>>>(cnt, offsets, order, xT, dwT);
    k_update_embed<<<256, 256, 0, stream>>>(dwT, ema_embed, smoothed, out_emb, out_ema);
    k_quantize_out<<<512, 256, 0, stream>>>(idx, embedT, out_q);
}

// Round 2
// 843.523 us; speedup vs baseline: 2.4756x; 2.4756x over previous
//
#include <hip/hip_runtime.h>
#include <math.h>

// VQ-VAE EMA vector quantizer, MI355X. Round 2: fp16-split MFMA distance GEMM.
// N=32768 rows, D=256, K=8192.

#define KC 8192
#define DD 256
#define NV 32768

typedef _Float16 f16;
typedef _Float16 f16x8 __attribute__((ext_vector_type(8)));
typedef _Float16 f16x4 __attribute__((ext_vector_type(4)));
typedef float f32x4 __attribute__((ext_vector_type(4)));

// ---------- x NCHW fp32 -> xh/xl f16 [n][d], plus sum(x^2) ----------
__global__ __launch_bounds__(256, 2) void k_convert_x(
    const float* __restrict__ x, f16* __restrict__ xh, f16* __restrict__ xl,
    float* __restrict__ lossAcc) {
    __shared__ float xs[256][68];
    __shared__ float red[4];
    const int t = threadIdx.x;
    const int n0 = blockIdx.x * 64;
    const int b = n0 >> 10;
    const int h0 = (n0 >> 5) & 31;
    {
        const int p = t >> 7, tt = t & 127;
        const int wq = (tt & 7) * 4, d0 = tt >> 3;
        const float* src = x + (size_t)b * 262144 + (size_t)(h0 + p) * 32 + wq;
        float s2 = 0.f;
        #pragma unroll
        for (int i = 0; i < 16; ++i) {
            int d = d0 + i * 16;
            float4 v = *(const float4*)(src + (size_t)d * 1024);
            *(float4*)&xs[d][p * 32 + wq] = v;
            s2 += v.x * v.x + v.y * v.y + v.z * v.z + v.w * v.w;
        }
        for (int off = 32; off > 0; off >>= 1) s2 += __shfl_xor(s2, off);
        if ((t & 63) == 0) red[t >> 6] = s2;
    }
    __syncthreads();
    if (t == 0) atomicAdd(&lossAcc[1], red[0] + red[1] + red[2] + red[3]);
    {
        const int rr = t & 3, c = t >> 2;
        #pragma unroll
        for (int i = 0; i < 16; ++i) {
            int r = rr + i * 4;
            f16x4 hv, lv;
            #pragma unroll
            for (int q = 0; q < 4; ++q) {
                float v = xs[c * 4 + q][r];
                f16 h = (f16)v;
                float rem = v - (float)h;
                hv[q] = h; lv[q] = (f16)rem;
            }
            *(f16x4*)(xh + (size_t)(n0 + r) * DD + c * 4) = hv;
            *(f16x4*)(xl + (size_t)(n0 + r) * DD + c * 4) = lv;
        }
    }
}

// ---------- embed fp32 [d][k] -> eh/el f16 [k][d] (transposed, split) ----------
__global__ void k_convert_e(const float* __restrict__ embed,
                            f16* __restrict__ eh, f16* __restrict__ el) {
    int kt = blockIdx.x & 255, dt = blockIdx.x >> 8;
    int k0 = kt * 32, d0 = dt * 32;
    __shared__ float tile[32][33];
    int t = threadIdx.x;
    int kk = t & 31, ii = t >> 5;
    for (int p = 0; p < 4; ++p) {
        int d = ii + p * 8;
        tile[d][kk] = embed[(size_t)(d0 + d) * KC + k0 + kk];
    }
    __syncthreads();
    int dv = t & 31, kk2 = t >> 5;
    for (int p = 0; p < 4; ++p) {
        int k = kk2 + p * 8;
        float v = tile[dv][k];
        f16 h = (f16)v;
        float rem = v - (float)h;
        eh[(size_t)(k0 + k) * DD + d0 + dv] = h;
        el[(size_t)(k0 + k) * DD + d0 + dv] = (f16)rem;
    }
}

// ---------- enorm[k] = sum_d embed[d,k]^2 (exact fp32) ----------
__global__ void k_enorm(const float* __restrict__ embed, float* __restrict__ enorm) {
    int k = blockIdx.x * 256 + threadIdx.x;
    float s = 0.f;
    for (int d = 0; d < DD; ++d) { float v = embed[(size_t)d * KC + k]; s += v * v; }
    enorm[k] = s;
}

// ---------- MFMA distance GEMM + per-strip argmin ----------
// block: 128 rows x 128 cols, K=256 in 8 chunks of 32. 4 waves, 2x2, each 64x64.
#define ASTRIDE 40
__global__ __launch_bounds__(256, 3) void k_argmin_mfma(
    const f16* __restrict__ xh, const f16* __restrict__ xl,
    const f16* __restrict__ eh, const f16* __restrict__ el,
    const float* __restrict__ enorm, unsigned long long* __restrict__ rowmin) {
    __shared__ f16 As[2 * 128 * ASTRIDE];
    __shared__ f16 Bs[2 * 128 * ASTRIDE];
    __shared__ float en_s[128];
    __shared__ float mval[128][2];
    __shared__ int   midx[128][2];
    const int t = threadIdx.x;
    const int n0 = blockIdx.x * 128;
    const int c0 = blockIdx.y * 128;
    if (t < 128) en_s[t] = enorm[c0 + t];

    const int lane = t & 63, wave = t >> 6;
    const int wr = wave >> 1, wc = wave & 1;
    const int m = lane & 15, quad = lane >> 4;
    const int rowbase = wr * 64, colbase = wc * 64;

    f32x4 acc[4][4];
    #pragma unroll
    for (int i = 0; i < 4; ++i)
        #pragma unroll
        for (int j = 0; j < 4; ++j) acc[i][j] = (f32x4){0.f, 0.f, 0.f, 0.f};

    const int srow = t >> 2, sdq = (t & 3) * 8;
    const f16* pxh = xh + (size_t)(n0 + srow) * DD + sdq;
    const f16* pxl = xl + (size_t)(n0 + srow) * DD + sdq;
    const f16* peh = eh + (size_t)(c0 + srow) * DD + sdq;
    const f16* pel = el + (size_t)(c0 + srow) * DD + sdq;

    for (int kt = 0; kt < 8; ++kt) {
        const int d0 = kt * 32;
        __syncthreads();
        #pragma unroll
        for (int rep = 0; rep < 2; ++rep) {
            const int row = srow + rep * 64;
            const int off = rep * 64 * DD;
            f16x8 a0 = *(const f16x8*)(pxh + off + d0);
            f16x8 a1 = *(const f16x8*)(pxl + off + d0);
            f16x8 b0 = *(const f16x8*)(peh + off + d0);
            f16x8 b1 = *(const f16x8*)(pel + off + d0);
            *(f16x8*)&As[row * ASTRIDE + sdq]          = a0;
            *(f16x8*)&As[(128 + row) * ASTRIDE + sdq]  = a1;
            *(f16x8*)&Bs[row * ASTRIDE + sdq]          = b0;
            *(f16x8*)&Bs[(128 + row) * ASTRIDE + sdq]  = b1;
        }
        __syncthreads();

        f16x8 ah[4], al[4];
        #pragma unroll
        for (int i = 0; i < 4; ++i) {
            int r = rowbase + i * 16 + m;
            ah[i] = *(const f16x8*)&As[r * ASTRIDE + quad * 8];
            al[i] = *(const f16x8*)&As[(128 + r) * ASTRIDE + quad * 8];
        }
        #pragma unroll
        for (int j = 0; j < 4; ++j) {
            int c = colbase + j * 16 + m;
            f16x8 bh = *(const f16x8*)&Bs[c * ASTRIDE + quad * 8];
            f16x8 bl = *(const f16x8*)&Bs[(128 + c) * ASTRIDE + quad * 8];
            #pragma unroll
            for (int i = 0; i < 4; ++i) {
                acc[i][j] = __builtin_amdgcn_mfma_f32_16x16x32_f16(ah[i], bh, acc[i][j], 0, 0, 0);
                acc[i][j] = __builtin_amdgcn_mfma_f32_16x16x32_f16(ah[i], bl, acc[i][j], 0, 0, 0);
                acc[i][j] = __builtin_amdgcn_mfma_f32_16x16x32_f16(al[i], bh, acc[i][j], 0, 0, 0);
            }
        }
    }

    // ---- argmin epilogue: per-lane over j, shfl over 16 col-lanes, LDS merge ----
    #pragma unroll
    for (int i = 0; i < 4; ++i) {
        #pragma unroll
        for (int r = 0; r < 4; ++r) {
            float v = 3.4e38f; int ii = 0;
            #pragma unroll
            for (int j = 0; j < 4; ++j) {
                int c = colbase + j * 16 + m;
                float dv = en_s[c] - 2.f * acc[i][j][r];
                if (dv < v) { v = dv; ii = c0 + c; }
            }
            #pragma unroll
            for (int off = 1; off < 16; off <<= 1) {
                float v2 = __shfl_xor(v, off);
                int i2 = __shfl_xor(ii, off);
                if (v2 < v || (v2 == v && i2 < ii)) { v = v2; ii = i2; }
            }
            if (m == 0) {
                int row = rowbase + i * 16 + quad * 4 + r;
                mval[row][wc] = v; midx[row][wc] = ii;
            }
        }
    }
    __syncthreads();
    if (t < 128) {
        float v0 = mval[t][0], v1 = mval[t][1];
        int i0 = midx[t][0], i1 = midx[t][1];
        if (v1 < v0 || (v1 == v0 && i1 < i0)) { v0 = v1; i0 = i1; }
        unsigned int u = __float_as_uint(v0);
        u = (u & 0x80000000u) ? ~u : (u | 0x80000000u);
        unsigned long long key = ((unsigned long long)u << 32) | (unsigned int)i0;
        atomicMin(rowmin + n0 + t, key);
    }
}

// ---------- decode rowmin -> idx, histogram, loss sum ----------
__global__ void k_finalize(const unsigned long long* __restrict__ rowmin,
                           int* __restrict__ idx, int* __restrict__ cnt,
                           float* __restrict__ lossAcc) {
    __shared__ float red[4];
    int t = threadIdx.x;
    int n = blockIdx.x * 256 + t;
    unsigned long long p = rowmin[n];
    unsigned int u = (unsigned int)(p >> 32);
    unsigned int u2 = (u & 0x80000000u) ? (u ^ 0x80000000u) : ~u;
    float v = __uint_as_float(u2);
    int i = (int)(unsigned int)(p & 0xFFFFFFFFu);
    idx[n] = i;
    atomicAdd(&cnt[i], 1);
    for (int off = 32; off > 0; off >>= 1) v += __shfl_xor(v, off);
    if ((t & 63) == 0) red[t >> 6] = v;
    __syncthreads();
    if (t == 0) atomicAdd(&lossAcc[0], red[0] + red[1] + red[2] + red[3]);
}

// ---------- single-block stats ----------
__global__ void k_stats(const int* __restrict__ cnt, const float* __restrict__ cluster_size,
                        const float* __restrict__ lossAcc,
                        float* __restrict__ out_ncs, float* __restrict__ out_loss,
                        float* __restrict__ out_perp,
                        float* __restrict__ smoothed, int* __restrict__ offsets) {
    __shared__ float rn[256], rp[256];
    __shared__ int rc[256];
    __shared__ int base_s[256];
    int t = threadIdx.x;
    float s_n = 0.f, s_pl = 0.f;
    int s_c = 0;
    float ncs_loc[32];
    #pragma unroll
    for (int i = 0; i < 32; ++i) {
        int k = t * 32 + i;
        int ci = cnt[k];
        float c = (float)ci;
        float ncs = cluster_size[k] * 0.99f + 0.01f * c;
        out_ncs[k] = ncs;
        ncs_loc[i] = ncs;
        s_n += ncs;
        float p = c * (1.0f / 32768.0f);
        s_pl += p * logf(p + 1e-10f);
        s_c += ci;
    }
    rn[t] = s_n; rp[t] = s_pl; rc[t] = s_c;
    for (int off = 128; off > 0; off >>= 1) {
        __syncthreads();
        if (t < off) { rn[t] += rn[t + off]; rp[t] += rp[t + off]; }
    }
    __syncthreads();
    float ntot = rn[0];
    if (t == 0) {
        out_loss[0] = 0.25f * (lossAcc[0] + lossAcc[1]) * (1.0f / 8388608.0f);
        out_perp[0] = expf(-rp[0]);
    }
    #pragma unroll
    for (int i = 0; i < 32; ++i) {
        int k = t * 32 + i;
        float ncs = ncs_loc[i];
        smoothed[k] = ntot * (ncs + 1e-5f) / (ntot + ncs * 1e-5f);
    }
    __syncthreads();
    if (t == 0) {
        int run = 0;
        for (int q = 0; q < 256; ++q) { base_s[q] = run; run += rc[q]; }
    }
    __syncthreads();
    int run = base_s[t];
    #pragma unroll
    for (int i = 0; i < 32; ++i) {
        int k = t * 32 + i;
        offsets[k] = run;
        run += cnt[k];
    }
}

// ---------- counting-sort scatter ----------
__global__ void k_scatter(const int* __restrict__ idx, const int* __restrict__ offsets,
                          int* __restrict__ cursor, int* __restrict__ order) {
    int n = blockIdx.x * 256 + threadIdx.x;
    int k = idx[n];
    int pos = offsets[k] + atomicAdd(&cursor[k], 1);
    order[pos] = n;
}

// ---------- dwT[k][d] (f16) = segment_sum of x ----------
__global__ void k_dw(const int* __restrict__ cnt, const int* __restrict__ offsets,
                     const int* __restrict__ order, const f16* __restrict__ xh,
                     const f16* __restrict__ xl, f16* __restrict__ dwT) {
    int k = blockIdx.x;
    int t = threadIdx.x;
    int c = cnt[k], base = offsets[k];
    float s = 0.f;
    for (int i = 0; i < c; ++i) {
        int n = order[base + i];
        s += (float)xh[(size_t)n * DD + t] + (float)xl[(size_t)n * DD + t];
    }
    dwT[(size_t)k * DD + t] = (f16)s;
}

// ---------- new_ema_embed / new_embed ----------
__global__ void k_update_embed(const f16* __restrict__ dwT, const float* __restrict__ ema_embed,
                               const float* __restrict__ smoothed,
                               float* __restrict__ out_embed, float* __restrict__ out_ema) {
    __shared__ float tile[32][260];
    int bx = blockIdx.x, t = threadIdx.x;
    int d0 = (bx & 7) * 32, k0 = (bx >> 3) * 256;
    {
        int kk = t >> 3, dq = (t & 7) * 4;
        for (int i = 0; i < 8; ++i) {
            int kl = kk + i * 32;
            f16x4 v = *(const f16x4*)(dwT + (size_t)(k0 + kl) * DD + d0 + dq);
            tile[dq + 0][kl] = (float)v[0]; tile[dq + 1][kl] = (float)v[1];
            tile[dq + 2][kl] = (float)v[2]; tile[dq + 3][kl] = (float)v[3];
        }
    }
    __syncthreads();
    float sm = smoothed[k0 + t];
    for (int dv = 0; dv < 32; ++dv) {
        size_t o = (size_t)(d0 + dv) * KC + k0 + t;
        float dw = tile[dv][t];
        float ne = ema_embed[o] * 0.99f + 0.01f * dw;
        out_ema[o] = ne;
        out_embed[o] = ne / sm;
    }
}

// ---------- quantize gather + NCHW writeback ----------
__global__ __launch_bounds__(256, 2) void k_quantize_out(
    const int* __restrict__ idx, const f16* __restrict__ eh, const f16* __restrict__ el,
    float* __restrict__ out) {
    __shared__ float q[256][68];
    __shared__ int li[64];
    int t = threadIdx.x;
    int n0 = blockIdx.x * 64;
    int b = n0 >> 10, h0 = (n0 >> 5) & 31;
    if (t < 64) li[t] = idx[n0 + t];
    __syncthreads();
    {
        int r = t >> 2, dq4 = (t & 3) * 4;
        const f16* srch = eh + (size_t)li[r] * DD;
        const f16* srcl = el + (size_t)li[r] * DD;
        for (int i = 0; i < 16; ++i) {
            int d = dq4 + i * 16;
            f16x4 hv = *(const f16x4*)(srch + d);
            f16x4 lv = *(const f16x4*)(srcl + d);
            q[d + 0][r] = (float)hv[0] + (float)lv[0];
            q[d + 1][r] = (float)hv[1] + (float)lv[1];
            q[d + 2][r] = (float)hv[2] + (float)lv[2];
            q[d + 3][r] = (float)hv[3] + (float)lv[3];
        }
    }
    __syncthreads();
    {
        int p = t >> 7, tt = t & 127;
        int wq = (tt & 7) * 4, d0 = tt >> 3;
        float* dst = out + (size_t)b * 262144 + (size_t)(h0 + p) * 32 + wq;
        for (int i = 0; i < 16; ++i) {
            int d = d0 + i * 16;
            float4 v = *(const float4*)&q[d][p * 32 + wq];
            *(float4*)(dst + (size_t)d * 1024) = v;
        }
    }
}

extern "C" void kernel_launch(void* const* d_in, const int* in_sizes, int n_in,
                              void* d_out, int out_size, void* d_ws, size_t ws_size,
                              hipStream_t stream) {
    (void)in_sizes; (void)n_in; (void)out_size; (void)ws_size;
    const float* x            = (const float*)d_in[0];
    const float* embed        = (const float*)d_in[1];
    const float* cluster_size = (const float*)d_in[2];
    const float* ema_embed    = (const float*)d_in[3];
    float* out = (float*)d_out;
    char* ws = (char*)d_ws;

    f16*   xh       = (f16*)  (ws + 0);           // 16,777,216
    f16*   xl       = (f16*)  (ws + 16777216);    // 16,777,216
    f16*   eh       = (f16*)  (ws + 33554432);    //  4,194,304
    f16*   el       = (f16*)  (ws + 37748736);    //  4,194,304
    float* enorm    = (float*)(ws + 41943040);    //     32,768
    float* smoothed = (float*)(ws + 41975808);    //     32,768
    int*   idx      = (int*)  (ws + 42008576);    //    131,072
    int*   cnt      = (int*)  (ws + 42139648);    //     32,768
    int*   cursor   = (int*)  (ws + 42172416);    //     32,768
    int*   offsets  = (int*)  (ws + 42205184);    //     32,768
    float* lossAcc  = (float*)(ws + 42237952);    //        256 (padded)
    unsigned long long* rowmin = (unsigned long long*)(ws + 42238208); // 262,144
    int*   order    = (int*)  (ws + 42238208);    // aliases rowmin (used after finalize)
    f16*   dwT      = (f16*)  (ws + 42500352);    //  4,194,304  -> total 46,694,656

    float* out_q    = out;
    float* out_loss = out + 8388608;
    float* out_perp = out + 8388609;
    float* out_ncs  = out + 8388610;
    float* out_emb  = out + 8396802;
    float* out_ema  = out + 10493954;

    hipMemsetAsync(cnt, 0, 65536, stream);          // cnt + cursor adjacent
    hipMemsetAsync(lossAcc, 0, 8, stream);
    hipMemsetAsync(rowmin, 0xFF, 262144, stream);

    k_convert_x<<<512, 256, 0, stream>>>(x, xh, xl, lossAcc);
    k_convert_e<<<2048, 256, 0, stream>>>(embed, eh, el);
    k_enorm<<<32, 256, 0, stream>>>(embed, enorm);
    k_argmin_mfma<<<dim3(256, 64), 256, 0, stream>>>(xh, xl, eh, el, enorm, rowmin);
    k_finalize<<<128, 256, 0, stream>>>(rowmin, idx, cnt, lossAcc);
    k_stats<<<1, 256, 0, stream>>>(cnt, cluster_size, lossAcc, out_ncs, out_loss, out_perp,
                                   smoothed, offsets);
    k_scatter<<<128, 256, 0, stream>>>(idx, offsets, cursor, order);
    k_dw<<<8192, 256, 0, stream>>>(cnt, offsets, order, xh, xl, dwT);
    k_update_embed<<<256, 256, 0, stream>>>(dwT, ema_embed, smoothed, out_emb, out_ema);
    k_quantize_out<<<512, 256, 0, stream>>>(idx, eh, el, out_q);
}